// Round 1
// baseline (305.442 us; speedup 1.0000x reference)
//
#include <hip/hip_runtime.h>

typedef __bf16 bf16x8 __attribute__((ext_vector_type(8)));
typedef float f32x4 __attribute__((ext_vector_type(4)));
typedef unsigned short us8 __attribute__((ext_vector_type(8)));

#define GAS __attribute__((address_space(1)))
#define LAS __attribute__((address_space(3)))

__device__ __forceinline__ unsigned short f32_to_bf16(float f) {
    unsigned int u = __float_as_uint(f);
    u += 0x7FFFu + ((u >> 16) & 1u);   // round-to-nearest-even
    return (unsigned short)(u >> 16);
}

__device__ __forceinline__ float bf16_to_f32(unsigned short h) {
    return __uint_as_float((unsigned int)h << 16);
}

__device__ __forceinline__ void load16(const unsigned short* g, unsigned short* l) {
    // async global->LDS, 16B per lane; LDS dest is wave-uniform base + lane*16
    __builtin_amdgcn_global_load_lds((GAS unsigned int*)g, (LAS unsigned int*)l, 16, 0, 0);
}

// ---------------------------------------------------------------------------
// prep (1024 threads): blocks [0,1536) convert x fp32->bf16 float4-wide
// (1536*1024 == 8192*768/4 exactly); blocks [1536,3264) transpose the three
// 768x768 weights to bf16 (24x24 tiles x 3 weights = 1728 blocks).
// ---------------------------------------------------------------------------
__global__ __launch_bounds__(1024) void prep(
    const float* __restrict__ x, unsigned short* __restrict__ Xbf,
    const float* __restrict__ W0, const float* __restrict__ W1, const float* __restrict__ W2,
    unsigned short* __restrict__ T0, unsigned short* __restrict__ T1, unsigned short* __restrict__ T2)
{
    __shared__ float tile[32][33];
    const int id = blockIdx.x;
    const int t = threadIdx.x;
    if (id < 1536) {
        int i = id * 1024 + t;
        float4 v = ((const float4*)x)[i];
        ushort4 o;
        o.x = f32_to_bf16(v.x); o.y = f32_to_bf16(v.y);
        o.z = f32_to_bf16(v.z); o.w = f32_to_bf16(v.w);
        ((ushort4*)Xbf)[i] = o;
    } else {
        const int tid = id - 1536;               // 0..1727
        const int z = tid / 576, rem = tid % 576;
        const int by = rem / 24, bx = rem % 24;
        const float* W = (z == 0) ? W0 : (z == 1) ? W1 : W2;
        unsigned short* T = (z == 0) ? T0 : (z == 1) ? T1 : T2;
        const int r0 = by * 32, c0 = bx * 32;
        const int tx = t & 31, ty = t >> 5;      // 32x32
        tile[ty][tx] = W[(size_t)(r0 + ty) * 768 + c0 + tx];
        __syncthreads();
        T[(size_t)(c0 + ty) * 768 + r0 + tx] = f32_to_bf16(tile[tx][ty]);
    }
}

// ---------------------------------------------------------------------------
// NT GEMM (m97 structure + XOR bank-swizzle): C = alpha * A[M,K] . B[N,K]^T
// (kept for the small QK / V^T projections)
// ---------------------------------------------------------------------------
template <typename CT>
__global__ __launch_bounds__(256) void gemm_nt(
    const unsigned short* __restrict__ A, const unsigned short* __restrict__ B,
    CT* __restrict__ C, int K, int lda, int ldb, int ldc,
    size_t sA, size_t sB, size_t sC, float alpha)
{
    A += (size_t)blockIdx.z * sA;
    B += (size_t)blockIdx.z * sB;
    C += (size_t)blockIdx.z * sC;
    const int m0 = blockIdx.y * 128;
    const int n0 = blockIdx.x * 128;
    const int t = threadIdx.x;
    const int lane = t & 63;
    const int w = t >> 6;
    const int wm = (w >> 1) * 64;   // wave row offset in tile
    const int wn = (w & 1) * 64;    // wave col offset in tile

    __shared__ unsigned short At[128 * 64];
    __shared__ unsigned short Bt[128 * 64];

    f32x4 acc[4][4];
#pragma unroll
    for (int i = 0; i < 4; ++i)
#pragma unroll
        for (int j = 0; j < 4; ++j) acc[i][j] = (f32x4){0.f, 0.f, 0.f, 0.f};

    const int r15 = lane & 15;
    const int qa = lane >> 4;       // fragment chunk index within 32-elem half

    for (int k0 = 0; k0 < K; k0 += 64) {
#pragma unroll
        for (int i = 0; i < 4; ++i) {
            const int c = i * 256 + t;            // LDS chunk id (8 bf16 each)
            const int row = c >> 3;
            const int cc = (c & 7) ^ (row & 7);   // swizzled global source chunk
            load16(A + (size_t)(m0 + row) * lda + k0 + cc * 8, &At[c * 8]);
            load16(B + (size_t)(n0 + row) * ldb + k0 + cc * 8, &Bt[c * 8]);
        }
        __syncthreads();

#pragma unroll
        for (int ks = 0; ks < 2; ++ks) {
            bf16x8 af[4], bf[4];
#pragma unroll
            for (int mi = 0; mi < 4; ++mi) {
                const int row = wm + mi * 16 + r15;
                af[mi] = *(const bf16x8*)&At[row * 64 + (((ks << 2) + qa) ^ (row & 7)) * 8];
            }
#pragma unroll
            for (int ni = 0; ni < 4; ++ni) {
                const int row = wn + ni * 16 + r15;
                bf[ni] = *(const bf16x8*)&Bt[row * 64 + (((ks << 2) + qa) ^ (row & 7)) * 8];
            }
#pragma unroll
            for (int mi = 0; mi < 4; ++mi)
#pragma unroll
                for (int ni = 0; ni < 4; ++ni)
                    acc[mi][ni] = __builtin_amdgcn_mfma_f32_16x16x32_bf16(
                        af[mi], bf[ni], acc[mi][ni], 0, 0, 0);
        }
        __syncthreads();
    }

    // epilogue: C/D layout col=lane&15, row=(lane>>4)*4+reg  [m89/m91 verified]
    const int cr = (lane >> 4) * 4;
#pragma unroll
    for (int mi = 0; mi < 4; ++mi) {
#pragma unroll
        for (int ni = 0; ni < 4; ++ni) {
            const int gm = m0 + wm + mi * 16 + cr;
            const int gn = n0 + wn + ni * 16 + r15;
#pragma unroll
            for (int r = 0; r < 4; ++r) {
                float v = alpha * acc[mi][ni][r];
                if constexpr (sizeof(CT) == 2)
                    C[(size_t)(gm + r) * ldc + gn] = (CT)f32_to_bf16(v);
                else
                    C[(size_t)(gm + r) * ldc + gn] = v;
            }
        }
    }
}

// ---------------------------------------------------------------------------
// 256x256-tile NT GEMM core, BK=64, 8 waves (2M x 4N, each 128x64 output),
// ring-2 LDS (128 KiB), 4 phases per K-tile:
//   phase = {ds_read frag subtile ; issue next-tile global_load_lds ;
//            s_barrier ; lgkmcnt(0) ; setprio(1) ; 16 MFMA ; setprio(0) ; s_barrier}
// Tile boundary: vmcnt(0)+s_barrier only -- next-tile loads were issued in
// phases 0-1 of the PREVIOUS tile (>=3 phases ~ 1900 cyc of distance, >> L2/HBM
// latency), so the drain is cheap. No __syncthreads() anywhere in the loop
// (it would force a full counter drain every phase).
// MFMA accumulation order over K identical to the old 128^2 kernel -> outputs
// are bitwise identical.
// ---------------------------------------------------------------------------
template <int NT, bool EXP>
__device__ __forceinline__ void gemm256_core(
    const unsigned short* __restrict__ A, const unsigned short* __restrict__ B,
    unsigned short* __restrict__ C,
    int m0, int n0, int lda, int ldb, int ldc, float alpha)
{
    __shared__ unsigned short As[2][256 * 64];
    __shared__ unsigned short Bs[2][256 * 64];

    const int t = threadIdx.x;          // 0..511
    const int lane = t & 63;
    const int w = t >> 6;               // 0..7
    const int wm = (w >> 2) * 128;      // 0 / 128
    const int wn = (w & 3) * 64;        // 0..192
    const int r15 = lane & 15;
    const int qa = lane >> 4;           // 0..3

    // Per-thread staging addresses (fixed): 4 A-loads + 4 B-loads per K-tile.
    // chunk c = i*512 + t ; row = c>>3 in [0,256) ; cc = (c&7)^(row&7) swizzle
    const unsigned short* srcA[4];
    const unsigned short* srcB[4];
    int dstOff[4];
#pragma unroll
    for (int i = 0; i < 4; ++i) {
        const int c = i * 512 + t;
        const int row = c >> 3;
        const int cc = (c & 7) ^ (row & 7);
        srcA[i] = A + (size_t)(m0 + row) * lda + cc * 8;
        srcB[i] = B + (size_t)(n0 + row) * ldb + cc * 8;
        dstOff[i] = c * 8;
    }

    auto stageA = [&](int b, int kbase) {
#pragma unroll
        for (int i = 0; i < 4; ++i)
            load16(srcA[i] + kbase, &As[b][dstOff[i]]);
    };
    auto stageB = [&](int b, int kbase) {
#pragma unroll
        for (int i = 0; i < 4; ++i)
            load16(srcB[i] + kbase, &Bs[b][dstOff[i]]);
    };

    // Issue tile 0 staging as early as possible.
    stageA(0, 0);
    stageB(0, 0);

    // Fragment LDS offsets (elements), same XOR swizzle as staging.
    int offA[8][2], offB[4][2];
#pragma unroll
    for (int mi = 0; mi < 8; ++mi) {
        const int row = wm + mi * 16 + r15;
#pragma unroll
        for (int ks = 0; ks < 2; ++ks)
            offA[mi][ks] = row * 64 + (((ks << 2) + qa) ^ (row & 7)) * 8;
    }
#pragma unroll
    for (int ni = 0; ni < 4; ++ni) {
        const int row = wn + ni * 16 + r15;
#pragma unroll
        for (int ks = 0; ks < 2; ++ks)
            offB[ni][ks] = row * 64 + (((ks << 2) + qa) ^ (row & 7)) * 8;
    }

    f32x4 acc[8][4];
#pragma unroll
    for (int i = 0; i < 8; ++i)
#pragma unroll
        for (int j = 0; j < 4; ++j) acc[i][j] = (f32x4){0.f, 0.f, 0.f, 0.f};

    for (int tt = 0; tt < NT; ++tt) {
        const int b = tt & 1;
        const bool st = (tt + 1) < NT;
        const int kn = (tt + 1) << 6;

        // tile boundary: my loads landed -> barrier -> everyone's loads landed
        asm volatile("s_waitcnt vmcnt(0)" ::: "memory");
        __builtin_amdgcn_s_barrier();
        asm volatile("" ::: "memory");

#pragma unroll
        for (int ks = 0; ks < 2; ++ks) {
#pragma unroll
            for (int mh = 0; mh < 2; ++mh) {
                // ---- phase (2*ks + mh) ----
                bf16x8 bf[4];
                if (mh == 0) {
#pragma unroll
                    for (int ni = 0; ni < 4; ++ni)
                        bf[ni] = *(const bf16x8*)&Bs[b][offB[ni][ks]];
                } else {
                    // re-read (registers would otherwise have to live across
                    // the barrier anyway; LDS re-read keeps pressure flat)
#pragma unroll
                    for (int ni = 0; ni < 4; ++ni)
                        bf[ni] = *(const bf16x8*)&Bs[b][offB[ni][ks]];
                }
                bf16x8 af[4];
#pragma unroll
                for (int i = 0; i < 4; ++i)
                    af[i] = *(const bf16x8*)&As[b][offA[mh * 4 + i][ks]];

                // issue next-tile staging early (phases 0 and 1 only)
                if (ks == 0 && st) {
                    if (mh == 0) stageA(b ^ 1, kn);
                    else         stageB(b ^ 1, kn);
                }

                __builtin_amdgcn_s_barrier();
                asm volatile("s_waitcnt lgkmcnt(0)" ::: "memory");
                __builtin_amdgcn_sched_barrier(0);
                __builtin_amdgcn_s_setprio(1);
#pragma unroll
                for (int i = 0; i < 4; ++i)
#pragma unroll
                    for (int ni = 0; ni < 4; ++ni)
                        acc[mh * 4 + i][ni] = __builtin_amdgcn_mfma_f32_16x16x32_bf16(
                            af[i], bf[ni], acc[mh * 4 + i][ni], 0, 0, 0);
                __builtin_amdgcn_s_setprio(0);
                __builtin_amdgcn_s_barrier();
            }
        }
    }

    // epilogue: C/D layout col=lane&15, row=(lane>>4)*4+reg
    const int cr = (lane >> 4) * 4;
#pragma unroll
    for (int mi = 0; mi < 8; ++mi) {
#pragma unroll
        for (int ni = 0; ni < 4; ++ni) {
            const int gm = m0 + wm + mi * 16 + cr;
            const int gn = n0 + wn + ni * 16 + r15;
#pragma unroll
            for (int r = 0; r < 4; ++r) {
                float v = alpha * acc[mi][ni][r];
                if constexpr (EXP) v = __expf(v);
                C[(size_t)(gm + r) * ldc + gn] = f32_to_bf16(v);
            }
        }
    }
}

// Sexp = exp(alpha * Q.K^T) bf16. grid (16,16,2), 512 threads.
__global__ __launch_bounds__(512, 2) void gemm_s_exp2(
    const unsigned short* __restrict__ Q, const unsigned short* __restrict__ Kb,
    unsigned short* __restrict__ Sexp, float alpha)
{
    const unsigned short* A = Q + (size_t)blockIdx.z * 3145728;
    const unsigned short* B = Kb + (size_t)blockIdx.z * 3145728;
    unsigned short* C = Sexp + (size_t)blockIdx.z * 16777216;
    gemm256_core<12, true>(A, B, C, blockIdx.y * 256, blockIdx.x * 256,
                           768, 768, 4096, alpha);
}

// Split-K O-GEMM. grid (3,16,8): z = split*2 + batch, K-chunk 1024.
// Part[z][4096][768] bf16, same layout/indexing as before.
__global__ __launch_bounds__(512, 2) void gemm_splitk2(
    const unsigned short* __restrict__ P, const unsigned short* __restrict__ Vt,
    unsigned short* __restrict__ Part)
{
    const int z = blockIdx.z;          // 0..7
    const int batch = z & 1;
    const int split = z >> 1;
    const unsigned short* A = P + (size_t)batch * 16777216 + (size_t)split * 1024;
    const unsigned short* B = Vt + (size_t)batch * 4096 + (size_t)split * 1024;
    unsigned short* C = Part + (size_t)z * 3145728;
    gemm256_core<16, false>(A, B, C, blockIdx.y * 256, blockIdx.x * 256,
                            4096, 8192, 768, 1.0f);
}

// ---------------------------------------------------------------------------
// Fused denominator + partial reduce + normalize. One block per output row g:
//   lsum = sum of Sexp[batch][r][:]   (4096 bf16, shuffle+LDS reduce)
//   out[g][c] = (sum_s Part[s*2+batch][r][c]) / lsum   (bf16 partials, fp32 out)
// ---------------------------------------------------------------------------
__global__ __launch_bounds__(256) void reduce_norm_rows(
    const unsigned short* __restrict__ Sexp, const unsigned short* __restrict__ Part,
    float* __restrict__ out)
{
    const int g = blockIdx.x;           // 0..8191
    const int batch = g >> 12;
    const int r = g & 4095;
    const int t = threadIdx.x;
    const int wv = t >> 6, ln = t & 63;

    // denominator
    const unsigned short* srow = Sexp + (size_t)batch * 16777216 + (size_t)r * 4096;
    us8 a = ((const us8*)srow)[t];
    us8 b = ((const us8*)srow)[t + 256];
    float s = 0.f;
#pragma unroll
    for (int j = 0; j < 8; ++j) s += bf16_to_f32(a[j]) + bf16_to_f32(b[j]);
#pragma unroll
    for (int off = 32; off > 0; off >>= 1) s += __shfl_down(s, off, 64);
    __shared__ float red[4];
    if (ln == 0) red[wv] = s;
    __syncthreads();
    const float inv = 1.f / (red[0] + red[1] + red[2] + red[3]);

    // reduce 4 bf16 partials + normalize; threads 0..191 each own 4 cols
    if (t < 192) {
        const int c = t * 4;
        float4 acc = {0.f, 0.f, 0.f, 0.f};
#pragma unroll
        for (int sgroup = 0; sgroup < 4; ++sgroup) {
            const unsigned short* p = Part
                + ((size_t)(sgroup * 2 + batch) * 4096 + r) * 768 + c;
            ushort4 u = *(const ushort4*)p;
            acc.x += bf16_to_f32(u.x);
            acc.y += bf16_to_f32(u.y);
            acc.z += bf16_to_f32(u.z);
            acc.w += bf16_to_f32(u.w);
        }
        float4 o;
        o.x = acc.x * inv; o.y = acc.y * inv; o.z = acc.z * inv; o.w = acc.w * inv;
        *(float4*)(out + (size_t)g * 768 + c) = o;
    }
}

// ---------------------------------------------------------------------------
extern "C" void kernel_launch(void* const* d_in, const int* in_sizes, int n_in,
                              void* d_out, int out_size, void* d_ws, size_t ws_size,
                              hipStream_t stream) {
    const float* x  = (const float*)d_in[0];   // [2,4096,768]
    const float* Wq = (const float*)d_in[1];   // [768,768]
    const float* Wk = (const float*)d_in[2];
    const float* Wv = (const float*)d_in[3];
    float* out = (float*)d_out;                // [2,4096,768] fp32

    char* base = (char*)d_ws;
    size_t off = 0;
    auto alloc = [&](size_t b) { char* p = base + off; off += (b + 255) & ~(size_t)255; return p; };

    unsigned short* Xbf = (unsigned short*)alloc(8192ull * 768 * 2);   // x as bf16
    unsigned short* WqT = (unsigned short*)alloc(768ull * 768 * 2);    // W^T bf16, x3 contiguous
    unsigned short* WkT = (unsigned short*)alloc(768ull * 768 * 2);
    unsigned short* WvT = (unsigned short*)alloc(768ull * 768 * 2);
    unsigned short* Qb  = (unsigned short*)alloc(8192ull * 768 * 2);   // Q,K bf16, contiguous
    unsigned short* Kb  = (unsigned short*)alloc(8192ull * 768 * 2);
    unsigned short* Vt  = (unsigned short*)alloc(768ull * 8192 * 2);   // V^T bf16 [768,8192]
    unsigned short* Sexp = (unsigned short*)alloc(2ull * 4096 * 4096 * 2); // exp(scores) bf16
    unsigned short* Part = (unsigned short*)alloc(8ull * 3145728 * 2); // split-K partials, bf16
    (void)ws_size; (void)in_sizes; (void)n_in; (void)out_size; (void)WkT;

    // 1) x -> bf16 and W -> W^T bf16 (fused, 1024-thread blocks)
    prep<<<dim3(3264), dim3(1024), 0, stream>>>(x, Xbf, Wq, Wk, Wv, WqT, WkT, WvT);
    // 2) Q,K = Xbf . W^T^T  (NT; z selects Wq/Wk)
    gemm_nt<unsigned short><<<dim3(6, 64, 2), dim3(256), 0, stream>>>(
        Xbf, WqT, Qb, 768, 768, 768, 768,
        /*sA*/ 0, /*sB*/ 589824, /*sC*/ 6291456, 1.0f);
    // 3) V^T = WvT . Xbf^T  (NT) -> [768, 8192]
    gemm_nt<unsigned short><<<dim3(64, 6, 1), dim3(256), 0, stream>>>(
        WvT, Xbf, Vt, 768, 768, 768, 8192, 0, 0, 0, 1.0f);
    // 4) Sexp = exp(Q.K^T / sqrt(768)) bf16 -- 256^2 pipelined core
    gemm_s_exp2<<<dim3(16, 16, 2), dim3(512), 0, stream>>>(
        Qb, Kb, Sexp, 0.03608439182435161f);
    // 5) O' = Sexp . V via 4-way split-K (z=8 with batches), bf16 partials
    gemm_splitk2<<<dim3(3, 16, 8), dim3(512), 0, stream>>>(Sexp, Vt, Part);
    // 6) fused denominator + partial-reduce + normalize
    reduce_norm_rows<<<dim3(8192), dim3(256), 0, stream>>>(Sexp, Part, out);
}

// Round 2
// 275.883 us; speedup vs baseline: 1.1071x; 1.1071x over previous
//
#include <hip/hip_runtime.h>

typedef __bf16 bf16x8 __attribute__((ext_vector_type(8)));
typedef float f32x4 __attribute__((ext_vector_type(4)));
typedef unsigned short us8 __attribute__((ext_vector_type(8)));

#define GAS __attribute__((address_space(1)))
#define LAS __attribute__((address_space(3)))

__device__ __forceinline__ unsigned short f32_to_bf16(float f) {
    unsigned int u = __float_as_uint(f);
    u += 0x7FFFu + ((u >> 16) & 1u);   // round-to-nearest-even
    return (unsigned short)(u >> 16);
}

__device__ __forceinline__ float bf16_to_f32(unsigned short h) {
    return __uint_as_float((unsigned int)h << 16);
}

__device__ __forceinline__ void load16(const unsigned short* g, unsigned short* l) {
    // async global->LDS, 16B per lane; LDS dest is wave-uniform base + lane*16
    __builtin_amdgcn_global_load_lds((GAS unsigned int*)g, (LAS unsigned int*)l, 16, 0, 0);
}

// ---------------------------------------------------------------------------
// prep (1024 threads): blocks [0,1536) convert x fp32->bf16 float4-wide
// (1536*1024 == 8192*768/4 exactly); blocks [1536,3264) transpose the three
// 768x768 weights to bf16 (24x24 tiles x 3 weights = 1728 blocks).
// ---------------------------------------------------------------------------
__global__ __launch_bounds__(1024) void prep(
    const float* __restrict__ x, unsigned short* __restrict__ Xbf,
    const float* __restrict__ W0, const float* __restrict__ W1, const float* __restrict__ W2,
    unsigned short* __restrict__ T0, unsigned short* __restrict__ T1, unsigned short* __restrict__ T2)
{
    __shared__ float tile[32][33];
    const int id = blockIdx.x;
    const int t = threadIdx.x;
    if (id < 1536) {
        int i = id * 1024 + t;
        float4 v = ((const float4*)x)[i];
        ushort4 o;
        o.x = f32_to_bf16(v.x); o.y = f32_to_bf16(v.y);
        o.z = f32_to_bf16(v.z); o.w = f32_to_bf16(v.w);
        ((ushort4*)Xbf)[i] = o;
    } else {
        const int tid = id - 1536;               // 0..1727
        const int z = tid / 576, rem = tid % 576;
        const int by = rem / 24, bx = rem % 24;
        const float* W = (z == 0) ? W0 : (z == 1) ? W1 : W2;
        unsigned short* T = (z == 0) ? T0 : (z == 1) ? T1 : T2;
        const int r0 = by * 32, c0 = bx * 32;
        const int tx = t & 31, ty = t >> 5;      // 32x32
        tile[ty][tx] = W[(size_t)(r0 + ty) * 768 + c0 + tx];
        __syncthreads();
        T[(size_t)(c0 + ty) * 768 + r0 + tx] = f32_to_bf16(tile[tx][ty]);
    }
}

// ---------------------------------------------------------------------------
// NT GEMM (m97 structure + XOR bank-swizzle): C = alpha * A[M,K] . B[N,K]^T
// (kept for the small QK / V^T projections)
// ---------------------------------------------------------------------------
template <typename CT>
__global__ __launch_bounds__(256) void gemm_nt(
    const unsigned short* __restrict__ A, const unsigned short* __restrict__ B,
    CT* __restrict__ C, int K, int lda, int ldb, int ldc,
    size_t sA, size_t sB, size_t sC, float alpha)
{
    A += (size_t)blockIdx.z * sA;
    B += (size_t)blockIdx.z * sB;
    C += (size_t)blockIdx.z * sC;
    const int m0 = blockIdx.y * 128;
    const int n0 = blockIdx.x * 128;
    const int t = threadIdx.x;
    const int lane = t & 63;
    const int w = t >> 6;
    const int wm = (w >> 1) * 64;   // wave row offset in tile
    const int wn = (w & 1) * 64;    // wave col offset in tile

    __shared__ unsigned short At[128 * 64];
    __shared__ unsigned short Bt[128 * 64];

    f32x4 acc[4][4];
#pragma unroll
    for (int i = 0; i < 4; ++i)
#pragma unroll
        for (int j = 0; j < 4; ++j) acc[i][j] = (f32x4){0.f, 0.f, 0.f, 0.f};

    const int r15 = lane & 15;
    const int qa = lane >> 4;       // fragment chunk index within 32-elem half

    for (int k0 = 0; k0 < K; k0 += 64) {
#pragma unroll
        for (int i = 0; i < 4; ++i) {
            const int c = i * 256 + t;            // LDS chunk id (8 bf16 each)
            const int row = c >> 3;
            const int cc = (c & 7) ^ (row & 7);   // swizzled global source chunk
            load16(A + (size_t)(m0 + row) * lda + k0 + cc * 8, &At[c * 8]);
            load16(B + (size_t)(n0 + row) * ldb + k0 + cc * 8, &Bt[c * 8]);
        }
        __syncthreads();

#pragma unroll
        for (int ks = 0; ks < 2; ++ks) {
            bf16x8 af[4], bf[4];
#pragma unroll
            for (int mi = 0; mi < 4; ++mi) {
                const int row = wm + mi * 16 + r15;
                af[mi] = *(const bf16x8*)&At[row * 64 + (((ks << 2) + qa) ^ (row & 7)) * 8];
            }
#pragma unroll
            for (int ni = 0; ni < 4; ++ni) {
                const int row = wn + ni * 16 + r15;
                bf[ni] = *(const bf16x8*)&Bt[row * 64 + (((ks << 2) + qa) ^ (row & 7)) * 8];
            }
#pragma unroll
            for (int mi = 0; mi < 4; ++mi)
#pragma unroll
                for (int ni = 0; ni < 4; ++ni)
                    acc[mi][ni] = __builtin_amdgcn_mfma_f32_16x16x32_bf16(
                        af[mi], bf[ni], acc[mi][ni], 0, 0, 0);
        }
        __syncthreads();
    }

    // epilogue: C/D layout col=lane&15, row=(lane>>4)*4+reg  [m89/m91 verified]
    const int cr = (lane >> 4) * 4;
#pragma unroll
    for (int mi = 0; mi < 4; ++mi) {
#pragma unroll
        for (int ni = 0; ni < 4; ++ni) {
            const int gm = m0 + wm + mi * 16 + cr;
            const int gn = n0 + wn + ni * 16 + r15;
#pragma unroll
            for (int r = 0; r < 4; ++r) {
                float v = alpha * acc[mi][ni][r];
                if constexpr (sizeof(CT) == 2)
                    C[(size_t)(gm + r) * ldc + gn] = (CT)f32_to_bf16(v);
                else
                    C[(size_t)(gm + r) * ldc + gn] = v;
            }
        }
    }
}

// ---------------------------------------------------------------------------
// 256x256-tile NT GEMM core v2. BK=64, 8 waves (2M x 4N, each 128x64 output),
// ring-2 LDS (128 KiB). 4 phases per K-tile = (ks, mh):
//   phase: { ds_read 4 A-frags (+4 B-frags at mh==0; B held in regs across
//            the mh pair) ; at phase 0 only: issue ALL 8 next-tile
//            global_load_lds ; s_barrier ; lgkmcnt(0) ; setprio(1) ;
//            16 MFMA ; setprio(0) ; s_barrier }
// Tile boundary is folded into phase 3's closing barrier: per-wave
// s_waitcnt vmcnt(0) BEFORE that barrier => at barrier release every wave's
// staging loads have landed (loads were issued 3 phases (~900+ cyc) earlier,
// >= HBM latency; operands are LLC-resident). No sched_barrier (m141), no
// redundant B re-reads (R1 bug). MFMA K-order per accumulator unchanged
// (ks=0 then ks=1) -> numerics identical to the m97-structure version.
// ---------------------------------------------------------------------------
template <int NT, bool EXP>
__device__ __forceinline__ void gemm256_core(
    const unsigned short* __restrict__ A, const unsigned short* __restrict__ B,
    unsigned short* __restrict__ C,
    int m0, int n0, int lda, int ldb, int ldc, float alpha)
{
    __shared__ unsigned short As[2][256 * 64];
    __shared__ unsigned short Bs[2][256 * 64];

    const int t = threadIdx.x;          // 0..511
    const int lane = t & 63;
    const int w = t >> 6;               // 0..7
    const int wm = (w >> 2) * 128;      // 0 / 128
    const int wn = (w & 3) * 64;        // 0..192
    const int r15 = lane & 15;
    const int qa = lane >> 4;           // 0..3

    // Per-thread staging addresses: 4 A-loads + 4 B-loads per K-tile.
    // chunk c = i*512 + t ; row = c>>3 in [0,256) ; cc = (c&7)^(row&7) swizzle
    const unsigned short* srcA[4];
    const unsigned short* srcB[4];
    int dstOff[4];
#pragma unroll
    for (int i = 0; i < 4; ++i) {
        const int c = i * 512 + t;
        const int row = c >> 3;
        const int cc = (c & 7) ^ (row & 7);
        srcA[i] = A + (size_t)(m0 + row) * lda + cc * 8;
        srcB[i] = B + (size_t)(n0 + row) * ldb + cc * 8;
        dstOff[i] = c * 8;
    }

    auto stageA = [&](int b, int kbase) {
#pragma unroll
        for (int i = 0; i < 4; ++i)
            load16(srcA[i] + kbase, &As[b][dstOff[i]]);
    };
    auto stageB = [&](int b, int kbase) {
#pragma unroll
        for (int i = 0; i < 4; ++i)
            load16(srcB[i] + kbase, &Bs[b][dstOff[i]]);
    };

    // Fragment LDS offsets (elements), same XOR swizzle as staging.
    int offA[8][2], offB[4][2];
#pragma unroll
    for (int mi = 0; mi < 8; ++mi) {
        const int row = wm + mi * 16 + r15;
#pragma unroll
        for (int ks = 0; ks < 2; ++ks)
            offA[mi][ks] = row * 64 + (((ks << 2) + qa) ^ (row & 7)) * 8;
    }
#pragma unroll
    for (int ni = 0; ni < 4; ++ni) {
        const int row = wn + ni * 16 + r15;
#pragma unroll
        for (int ks = 0; ks < 2; ++ks)
            offB[ni][ks] = row * 64 + (((ks << 2) + qa) ^ (row & 7)) * 8;
    }

    f32x4 acc[8][4];
#pragma unroll
    for (int i = 0; i < 8; ++i)
#pragma unroll
        for (int j = 0; j < 4; ++j) acc[i][j] = (f32x4){0.f, 0.f, 0.f, 0.f};

    // Prologue: stage tile 0, drain, sync.
    stageA(0, 0);
    stageB(0, 0);
    asm volatile("s_waitcnt vmcnt(0)" ::: "memory");
    __builtin_amdgcn_s_barrier();

    for (int tt = 0; tt < NT; ++tt) {
        const int b = tt & 1;
        const bool st = (tt + 1) < NT;
        const int kn = (tt + 1) << 6;

#pragma unroll
        for (int ks = 0; ks < 2; ++ks) {
            bf16x8 bB[4];                      // B-frags live across the mh pair
#pragma unroll
            for (int mh = 0; mh < 2; ++mh) {
                // ---- phase (2*ks + mh) ----
                bf16x8 aA[4];
#pragma unroll
                for (int i = 0; i < 4; ++i)
                    aA[i] = *(const bf16x8*)&As[b][offA[mh * 4 + i][ks]];
                if (mh == 0) {
#pragma unroll
                    for (int ni = 0; ni < 4; ++ni)
                        bB[ni] = *(const bf16x8*)&Bs[b][offB[ni][ks]];
                }
                // phase 0 only: issue ALL next-tile staging (max vmcnt distance)
                if (ks == 0 && mh == 0 && st) {
                    stageA(b ^ 1, kn);
                    stageB(b ^ 1, kn);
                }

                __builtin_amdgcn_s_barrier();
                asm volatile("s_waitcnt lgkmcnt(0)" ::: "memory");
                __builtin_amdgcn_s_setprio(1);
#pragma unroll
                for (int i = 0; i < 4; ++i)
#pragma unroll
                    for (int ni = 0; ni < 4; ++ni)
                        acc[mh * 4 + i][ni] = __builtin_amdgcn_mfma_f32_16x16x32_bf16(
                            aA[i], bB[ni], acc[mh * 4 + i][ni], 0, 0, 0);
                __builtin_amdgcn_s_setprio(0);
                if (ks == 1 && mh == 1) {
                    // folded tile boundary: my stages landed -> barrier ->
                    // everyone's stages landed
                    asm volatile("s_waitcnt vmcnt(0)" ::: "memory");
                    __builtin_amdgcn_s_barrier();
                } else {
                    __builtin_amdgcn_s_barrier();
                }
            }
        }
    }

    // epilogue: C/D layout col=lane&15, row=(lane>>4)*4+reg
    const int cr = (lane >> 4) * 4;
#pragma unroll
    for (int mi = 0; mi < 8; ++mi) {
#pragma unroll
        for (int ni = 0; ni < 4; ++ni) {
            const int gm = m0 + wm + mi * 16 + cr;
            const int gn = n0 + wn + ni * 16 + r15;
#pragma unroll
            for (int r = 0; r < 4; ++r) {
                float v = alpha * acc[mi][ni][r];
                if constexpr (EXP) v = __expf(v);
                C[(size_t)(gm + r) * ldc + gn] = f32_to_bf16(v);
            }
        }
    }
}

// Sexp = exp(alpha * Q.K^T) bf16. grid (16,16,2) = 512 blocks (2 clean
// rounds at 1 block/CU), 512 threads.
__global__ __launch_bounds__(512, 2) void gemm_s_exp2(
    const unsigned short* __restrict__ Q, const unsigned short* __restrict__ Kb,
    unsigned short* __restrict__ Sexp, float alpha)
{
    const unsigned short* A = Q + (size_t)blockIdx.z * 3145728;
    const unsigned short* B = Kb + (size_t)blockIdx.z * 3145728;
    unsigned short* C = Sexp + (size_t)blockIdx.z * 16777216;
    gemm256_core<12, true>(A, B, C, blockIdx.y * 256, blockIdx.x * 256,
                           768, 768, 4096, alpha);
}

// Split-K O-GEMM. grid (3,16,4) = 192 blocks (single round): z = split*2+batch,
// split in {0,1}, K-chunk 2048 (NT=32). Part[z][4096][768] bf16.
__global__ __launch_bounds__(512, 2) void gemm_splitk2(
    const unsigned short* __restrict__ P, const unsigned short* __restrict__ Vt,
    unsigned short* __restrict__ Part)
{
    const int z = blockIdx.z;          // 0..3
    const int batch = z & 1;
    const int split = z >> 1;          // 0..1
    const unsigned short* A = P + (size_t)batch * 16777216 + (size_t)split * 2048;
    const unsigned short* B = Vt + (size_t)batch * 4096 + (size_t)split * 2048;
    unsigned short* C = Part + (size_t)z * 3145728;
    gemm256_core<32, false>(A, B, C, blockIdx.y * 256, blockIdx.x * 256,
                            4096, 8192, 768, 1.0f);
}

// ---------------------------------------------------------------------------
// Fused denominator + partial reduce + normalize. One block per output row g:
//   lsum = sum of Sexp[batch][r][:]   (4096 bf16, shuffle+LDS reduce)
//   out[g][c] = (sum_s Part[s*2+batch][r][c]) / lsum   (bf16 partials, fp32 out)
// ---------------------------------------------------------------------------
__global__ __launch_bounds__(256) void reduce_norm_rows(
    const unsigned short* __restrict__ Sexp, const unsigned short* __restrict__ Part,
    float* __restrict__ out)
{
    const int g = blockIdx.x;           // 0..8191
    const int batch = g >> 12;
    const int r = g & 4095;
    const int t = threadIdx.x;
    const int wv = t >> 6, ln = t & 63;

    // denominator
    const unsigned short* srow = Sexp + (size_t)batch * 16777216 + (size_t)r * 4096;
    us8 a = ((const us8*)srow)[t];
    us8 b = ((const us8*)srow)[t + 256];
    float s = 0.f;
#pragma unroll
    for (int j = 0; j < 8; ++j) s += bf16_to_f32(a[j]) + bf16_to_f32(b[j]);
#pragma unroll
    for (int off = 32; off > 0; off >>= 1) s += __shfl_down(s, off, 64);
    __shared__ float red[4];
    if (ln == 0) red[wv] = s;
    __syncthreads();
    const float inv = 1.f / (red[0] + red[1] + red[2] + red[3]);

    // reduce 2 bf16 partials + normalize; threads 0..191 each own 4 cols
    if (t < 192) {
        const int c = t * 4;
        float4 acc = {0.f, 0.f, 0.f, 0.f};
#pragma unroll
        for (int sgroup = 0; sgroup < 2; ++sgroup) {
            const unsigned short* p = Part
                + ((size_t)(sgroup * 2 + batch) * 4096 + r) * 768 + c;
            ushort4 u = *(const ushort4*)p;
            acc.x += bf16_to_f32(u.x);
            acc.y += bf16_to_f32(u.y);
            acc.z += bf16_to_f32(u.z);
            acc.w += bf16_to_f32(u.w);
        }
        float4 o;
        o.x = acc.x * inv; o.y = acc.y * inv; o.z = acc.z * inv; o.w = acc.w * inv;
        *(float4*)(out + (size_t)g * 768 + c) = o;
    }
}

// ---------------------------------------------------------------------------
extern "C" void kernel_launch(void* const* d_in, const int* in_sizes, int n_in,
                              void* d_out, int out_size, void* d_ws, size_t ws_size,
                              hipStream_t stream) {
    const float* x  = (const float*)d_in[0];   // [2,4096,768]
    const float* Wq = (const float*)d_in[1];   // [768,768]
    const float* Wk = (const float*)d_in[2];
    const float* Wv = (const float*)d_in[3];
    float* out = (float*)d_out;                // [2,4096,768] fp32

    char* base = (char*)d_ws;
    size_t off = 0;
    auto alloc = [&](size_t b) { char* p = base + off; off += (b + 255) & ~(size_t)255; return p; };

    unsigned short* Xbf = (unsigned short*)alloc(8192ull * 768 * 2);   // x as bf16
    unsigned short* WqT = (unsigned short*)alloc(768ull * 768 * 2);    // W^T bf16, x3 contiguous
    unsigned short* WkT = (unsigned short*)alloc(768ull * 768 * 2);
    unsigned short* WvT = (unsigned short*)alloc(768ull * 768 * 2);
    unsigned short* Qb  = (unsigned short*)alloc(8192ull * 768 * 2);   // Q,K bf16, contiguous
    unsigned short* Kb  = (unsigned short*)alloc(8192ull * 768 * 2);
    unsigned short* Vt  = (unsigned short*)alloc(768ull * 8192 * 2);   // V^T bf16 [768,8192]
    unsigned short* Sexp = (unsigned short*)alloc(2ull * 4096 * 4096 * 2); // exp(scores) bf16
    unsigned short* Part = (unsigned short*)alloc(4ull * 3145728 * 2); // split-K partials, bf16
    (void)ws_size; (void)in_sizes; (void)n_in; (void)out_size; (void)WkT;

    // 1) x -> bf16 and W -> W^T bf16 (fused, 1024-thread blocks)
    prep<<<dim3(3264), dim3(1024), 0, stream>>>(x, Xbf, Wq, Wk, Wv, WqT, WkT, WvT);
    // 2) Q,K = Xbf . W^T^T  (NT; z selects Wq/Wk)
    gemm_nt<unsigned short><<<dim3(6, 64, 2), dim3(256), 0, stream>>>(
        Xbf, WqT, Qb, 768, 768, 768, 768,
        /*sA*/ 0, /*sB*/ 589824, /*sC*/ 6291456, 1.0f);
    // 3) V^T = WvT . Xbf^T  (NT) -> [768, 8192]
    gemm_nt<unsigned short><<<dim3(64, 6, 1), dim3(256), 0, stream>>>(
        WvT, Xbf, Vt, 768, 768, 768, 8192, 0, 0, 0, 1.0f);
    // 4) Sexp = exp(Q.K^T / sqrt(768)) bf16 -- 256^2 pipelined core v2
    gemm_s_exp2<<<dim3(16, 16, 2), dim3(512), 0, stream>>>(
        Qb, Kb, Sexp, 0.03608439182435161f);
    // 5) O' = Sexp . V via 2-way split-K (z=4 with batches), bf16 partials
    gemm_splitk2<<<dim3(3, 16, 4), dim3(512), 0, stream>>>(Sexp, Vt, Part);
    // 6) fused denominator + partial-reduce + normalize
    reduce_norm_rows<<<dim3(8192), dim3(256), 0, stream>>>(Sexp, Part, out);
}

// Round 3
// 270.520 us; speedup vs baseline: 1.1291x; 1.0198x over previous
//
#include <hip/hip_runtime.h>

typedef __bf16 bf16x8 __attribute__((ext_vector_type(8)));
typedef float f32x4 __attribute__((ext_vector_type(4)));
typedef unsigned short us8 __attribute__((ext_vector_type(8)));

#define GAS __attribute__((address_space(1)))
#define LAS __attribute__((address_space(3)))

__device__ __forceinline__ unsigned short f32_to_bf16(float f) {
    unsigned int u = __float_as_uint(f);
    u += 0x7FFFu + ((u >> 16) & 1u);   // round-to-nearest-even
    return (unsigned short)(u >> 16);
}

__device__ __forceinline__ float bf16_to_f32(unsigned short h) {
    return __uint_as_float((unsigned int)h << 16);
}

__device__ __forceinline__ void load16(const unsigned short* g, unsigned short* l) {
    // async global->LDS, 16B per lane; LDS dest is wave-uniform base + lane*16
    __builtin_amdgcn_global_load_lds((GAS unsigned int*)g, (LAS unsigned int*)l, 16, 0, 0);
}

// ---------------------------------------------------------------------------
// prep (1024 threads): blocks [0,1536) convert x fp32->bf16 float4-wide
// (1536*1024 == 8192*768/4 exactly); blocks [1536,3264) transpose the three
// 768x768 weights to bf16 (24x24 tiles x 3 weights = 1728 blocks).
// ---------------------------------------------------------------------------
__global__ __launch_bounds__(1024) void prep(
    const float* __restrict__ x, unsigned short* __restrict__ Xbf,
    const float* __restrict__ W0, const float* __restrict__ W1, const float* __restrict__ W2,
    unsigned short* __restrict__ T0, unsigned short* __restrict__ T1, unsigned short* __restrict__ T2)
{
    __shared__ float tile[32][33];
    const int id = blockIdx.x;
    const int t = threadIdx.x;
    if (id < 1536) {
        int i = id * 1024 + t;
        float4 v = ((const float4*)x)[i];
        ushort4 o;
        o.x = f32_to_bf16(v.x); o.y = f32_to_bf16(v.y);
        o.z = f32_to_bf16(v.z); o.w = f32_to_bf16(v.w);
        ((ushort4*)Xbf)[i] = o;
    } else {
        const int tid = id - 1536;               // 0..1727
        const int z = tid / 576, rem = tid % 576;
        const int by = rem / 24, bx = rem % 24;
        const float* W = (z == 0) ? W0 : (z == 1) ? W1 : W2;
        unsigned short* T = (z == 0) ? T0 : (z == 1) ? T1 : T2;
        const int r0 = by * 32, c0 = bx * 32;
        const int tx = t & 31, ty = t >> 5;      // 32x32
        tile[ty][tx] = W[(size_t)(r0 + ty) * 768 + c0 + tx];
        __syncthreads();
        T[(size_t)(c0 + ty) * 768 + r0 + tx] = f32_to_bf16(tile[tx][ty]);
    }
}

// ---------------------------------------------------------------------------
// NT GEMM (m97 structure + XOR bank-swizzle): C = alpha * A[M,K] . B[N,K]^T
// (kept for the small QK / V^T projections)
// ---------------------------------------------------------------------------
template <typename CT>
__global__ __launch_bounds__(256) void gemm_nt(
    const unsigned short* __restrict__ A, const unsigned short* __restrict__ B,
    CT* __restrict__ C, int K, int lda, int ldb, int ldc,
    size_t sA, size_t sB, size_t sC, float alpha)
{
    A += (size_t)blockIdx.z * sA;
    B += (size_t)blockIdx.z * sB;
    C += (size_t)blockIdx.z * sC;
    const int m0 = blockIdx.y * 128;
    const int n0 = blockIdx.x * 128;
    const int t = threadIdx.x;
    const int lane = t & 63;
    const int w = t >> 6;
    const int wm = (w >> 1) * 64;   // wave row offset in tile
    const int wn = (w & 1) * 64;    // wave col offset in tile

    __shared__ unsigned short At[128 * 64];
    __shared__ unsigned short Bt[128 * 64];

    f32x4 acc[4][4];
#pragma unroll
    for (int i = 0; i < 4; ++i)
#pragma unroll
        for (int j = 0; j < 4; ++j) acc[i][j] = (f32x4){0.f, 0.f, 0.f, 0.f};

    const int r15 = lane & 15;
    const int qa = lane >> 4;       // fragment chunk index within 32-elem half

    for (int k0 = 0; k0 < K; k0 += 64) {
#pragma unroll
        for (int i = 0; i < 4; ++i) {
            const int c = i * 256 + t;            // LDS chunk id (8 bf16 each)
            const int row = c >> 3;
            const int cc = (c & 7) ^ (row & 7);   // swizzled global source chunk
            load16(A + (size_t)(m0 + row) * lda + k0 + cc * 8, &At[c * 8]);
            load16(B + (size_t)(n0 + row) * ldb + k0 + cc * 8, &Bt[c * 8]);
        }
        __syncthreads();

#pragma unroll
        for (int ks = 0; ks < 2; ++ks) {
            bf16x8 af[4], bf[4];
#pragma unroll
            for (int mi = 0; mi < 4; ++mi) {
                const int row = wm + mi * 16 + r15;
                af[mi] = *(const bf16x8*)&At[row * 64 + (((ks << 2) + qa) ^ (row & 7)) * 8];
            }
#pragma unroll
            for (int ni = 0; ni < 4; ++ni) {
                const int row = wn + ni * 16 + r15;
                bf[ni] = *(const bf16x8*)&Bt[row * 64 + (((ks << 2) + qa) ^ (row & 7)) * 8];
            }
#pragma unroll
            for (int mi = 0; mi < 4; ++mi)
#pragma unroll
                for (int ni = 0; ni < 4; ++ni)
                    acc[mi][ni] = __builtin_amdgcn_mfma_f32_16x16x32_bf16(
                        af[mi], bf[ni], acc[mi][ni], 0, 0, 0);
        }
        __syncthreads();
    }

    // epilogue: C/D layout col=lane&15, row=(lane>>4)*4+reg  [m89/m91 verified]
    const int cr = (lane >> 4) * 4;
#pragma unroll
    for (int mi = 0; mi < 4; ++mi) {
#pragma unroll
        for (int ni = 0; ni < 4; ++ni) {
            const int gm = m0 + wm + mi * 16 + cr;
            const int gn = n0 + wn + ni * 16 + r15;
#pragma unroll
            for (int r = 0; r < 4; ++r) {
                float v = alpha * acc[mi][ni][r];
                if constexpr (sizeof(CT) == 2)
                    C[(size_t)(gm + r) * ldc + gn] = (CT)f32_to_bf16(v);
                else
                    C[(size_t)(gm + r) * ldc + gn] = v;
            }
        }
    }
}

// ---------------------------------------------------------------------------
// 256xBN-tile NT GEMM core v3. BK=64, 8 waves (2M x 4N, each 128 x BN/4).
// Ring-2 LDS, 2-tile prefetch, counted vmcnt (T4):
//   prologue stages tiles 0 AND 1; at the end of tile t the buffer just
//   consumed is restaged with tile t+2 -> issue-to-wait distance = 4 full
//   phases (>= HBM latency). Steady-state wait is vmcnt(L) (L = per-thread
//   loads/tile), never 0 except the last tile (whose loads are 2 tiles old).
// 4 phases per K-tile = (ks, mh):
//   { ds_read 4 A-frags (+BN64 B-frags at mh==0, held in regs across the
//     pair) ; s_barrier ; lgkmcnt(0) ; setprio(1) ; 4*BN64 MFMA ;
//     setprio(0) ; s_barrier }
// MFMA K-order per accumulator unchanged -> numerics identical.
// ---------------------------------------------------------------------------
template <int NT, int BN64, bool EXP>
__device__ __forceinline__ void gemm256_core(
    const unsigned short* __restrict__ A, const unsigned short* __restrict__ B,
    unsigned short* __restrict__ C,
    int m0, int n0, int lda, int ldb, int ldc, float alpha)
{
    constexpr int BN = BN64 * 64;        // 256 or 192
    __shared__ unsigned short As[2][256 * 64];
    __shared__ unsigned short Bs[2][BN * 64];

    const int t = threadIdx.x;          // 0..511
    const int lane = t & 63;
    const int w = t >> 6;               // 0..7
    const int wm = (w >> 2) * 128;      // 0 / 128
    const int wn = (w & 3) * (BN / 4);  // wave col offset
    const int r15 = lane & 15;
    const int qa = lane >> 4;           // 0..3

    // Per-thread staging addresses: 4 A-loads + BN64 B-loads per K-tile.
    const unsigned short* srcA[4];
    int dstA[4];
#pragma unroll
    for (int i = 0; i < 4; ++i) {
        const int c = i * 512 + t;
        const int row = c >> 3;
        const int cc = (c & 7) ^ (row & 7);
        srcA[i] = A + (size_t)(m0 + row) * lda + cc * 8;
        dstA[i] = c * 8;
    }
    const unsigned short* srcB[BN64];
    int dstB[BN64];
#pragma unroll
    for (int i = 0; i < BN64; ++i) {
        const int c = i * 512 + t;
        const int row = c >> 3;
        const int cc = (c & 7) ^ (row & 7);
        srcB[i] = B + (size_t)(n0 + row) * ldb + cc * 8;
        dstB[i] = c * 8;
    }

    auto stage = [&](int buf, int kbase) {
#pragma unroll
        for (int i = 0; i < 4; ++i)
            load16(srcA[i] + kbase, &As[buf][dstA[i]]);
#pragma unroll
        for (int i = 0; i < BN64; ++i)
            load16(srcB[i] + kbase, &Bs[buf][dstB[i]]);
    };

    // Fragment LDS offsets (elements), same XOR swizzle as staging.
    int offA[8][2], offB[BN64][2];
#pragma unroll
    for (int mi = 0; mi < 8; ++mi) {
        const int row = wm + mi * 16 + r15;
#pragma unroll
        for (int ks = 0; ks < 2; ++ks)
            offA[mi][ks] = row * 64 + (((ks << 2) + qa) ^ (row & 7)) * 8;
    }
#pragma unroll
    for (int ni = 0; ni < BN64; ++ni) {
        const int row = wn + ni * 16 + r15;
#pragma unroll
        for (int ks = 0; ks < 2; ++ks)
            offB[ni][ks] = row * 64 + (((ks << 2) + qa) ^ (row & 7)) * 8;
    }

    f32x4 acc[8][BN64];
#pragma unroll
    for (int i = 0; i < 8; ++i)
#pragma unroll
        for (int j = 0; j < BN64; ++j) acc[i][j] = (f32x4){0.f, 0.f, 0.f, 0.f};

    // Prologue: stage tiles 0 and 1 (fills the ring).
    stage(0, 0);
    stage(1, 64);

    for (int tt = 0; tt < NT; ++tt) {
        const int b = tt & 1;

        // Counted wait: everything except the newest L loads (tile t+1's) has
        // retired => tile t's staging landed. Last tile: full drain (its loads
        // are 2 tiles old by now -> cheap).
        if (tt == NT - 1) {
            asm volatile("s_waitcnt vmcnt(0)" ::: "memory");
        } else if constexpr (BN64 == 4) {
            asm volatile("s_waitcnt vmcnt(8)" ::: "memory");
        } else {
            asm volatile("s_waitcnt vmcnt(7)" ::: "memory");
        }
        __builtin_amdgcn_s_barrier();

#pragma unroll
        for (int ks = 0; ks < 2; ++ks) {
            bf16x8 bB[BN64];                   // B-frags live across the mh pair
#pragma unroll
            for (int mh = 0; mh < 2; ++mh) {
                bf16x8 aA[4];
#pragma unroll
                for (int i = 0; i < 4; ++i)
                    aA[i] = *(const bf16x8*)&As[b][offA[mh * 4 + i][ks]];
                if (mh == 0) {
#pragma unroll
                    for (int ni = 0; ni < BN64; ++ni)
                        bB[ni] = *(const bf16x8*)&Bs[b][offB[ni][ks]];
                }

                __builtin_amdgcn_s_barrier();
                asm volatile("s_waitcnt lgkmcnt(0)" ::: "memory");
                __builtin_amdgcn_s_setprio(1);
#pragma unroll
                for (int i = 0; i < 4; ++i)
#pragma unroll
                    for (int ni = 0; ni < BN64; ++ni)
                        acc[mh * 4 + i][ni] = __builtin_amdgcn_mfma_f32_16x16x32_bf16(
                            aA[i], bB[ni], acc[mh * 4 + i][ni], 0, 0, 0);
                __builtin_amdgcn_s_setprio(0);
                __builtin_amdgcn_s_barrier();
            }
        }

        // Restage the buffer just consumed with tile t+2. After the closing
        // barrier above, every wave has finished its LDS reads of buf b.
        if (tt + 2 < NT) stage(b, (tt + 2) << 6);
    }

    // epilogue: C/D layout col=lane&15, row=(lane>>4)*4+reg
    const int cr = (lane >> 4) * 4;
#pragma unroll
    for (int mi = 0; mi < 8; ++mi) {
#pragma unroll
        for (int ni = 0; ni < BN64; ++ni) {
            const int gm = m0 + wm + mi * 16 + cr;
            const int gn = n0 + wn + ni * 16 + r15;
#pragma unroll
            for (int r = 0; r < 4; ++r) {
                float v = alpha * acc[mi][ni][r];
                if constexpr (EXP) v = __expf(v);
                C[(size_t)(gm + r) * ldc + gn] = f32_to_bf16(v);
            }
        }
    }
}

// Sexp = exp(alpha * Q.K^T) bf16. 1-D grid 512, 512 threads. XCD swizzle:
// xcd = (x>>3) | ((y>>3)<<1) | (batch<<2); local = (x&7) + 8*(y&7).
// Within an XCD: 8 x-blocks share each Q-panel, 8 y-blocks share each K-panel.
__global__ __launch_bounds__(512, 2) void gemm_s_exp2(
    const unsigned short* __restrict__ Q, const unsigned short* __restrict__ Kb,
    unsigned short* __restrict__ Sexp, float alpha)
{
    const int f = blockIdx.x;            // 0..511
    const int xcd = f & 7;
    const int local = f >> 3;            // 0..63
    const int x = (xcd & 1) * 8 + (local & 7);
    const int y = ((xcd >> 1) & 1) * 8 + (local >> 3);
    const int bb = xcd >> 2;
    const unsigned short* A = Q + (size_t)bb * 3145728;
    const unsigned short* B = Kb + (size_t)bb * 3145728;
    unsigned short* C = Sexp + (size_t)bb * 16777216;
    gemm256_core<12, 4, true>(A, B, C, y * 256, x * 256, 768, 768, 4096, alpha);
}

// Split-K O-GEMM, BN=192 -> grid 4x16x4 = 256 blocks = EXACT one round.
// z = split*2 + batch, K-chunk 2048 (NT=32). Part[z][4096][768] bf16.
// XCD swizzle: xcd = 2*z + (y>>3); local = j + 4*(y&7). Within an XCD all
// 4 n-blocks share each A(Sexp)-panel and 8 y-blocks share each V-panel.
__global__ __launch_bounds__(512, 2) void gemm_splitk2(
    const unsigned short* __restrict__ P, const unsigned short* __restrict__ Vt,
    unsigned short* __restrict__ Part)
{
    const int f = blockIdx.x;            // 0..255
    const int xcd = f & 7;
    const int local = f >> 3;            // 0..31
    const int j = local & 3;             // n-block 0..3
    const int y = (xcd & 1) * 8 + (local >> 2);   // m-block 0..15
    const int z = xcd >> 1;              // 0..3
    const int batch = z & 1;
    const int split = z >> 1;            // 0..1
    const unsigned short* A = P + (size_t)batch * 16777216 + (size_t)split * 2048;
    const unsigned short* B = Vt + (size_t)batch * 4096 + (size_t)split * 2048;
    unsigned short* C = Part + (size_t)z * 3145728;
    gemm256_core<32, 3, false>(A, B, C, y * 256, j * 192, 4096, 8192, 768, 1.0f);
}

// ---------------------------------------------------------------------------
// Fused denominator + partial reduce + normalize. One block per output row g:
//   lsum = sum of Sexp[batch][r][:]   (4096 bf16, shuffle+LDS reduce)
//   out[g][c] = (sum_s Part[s*2+batch][r][c]) / lsum   (bf16 partials, fp32 out)
// ---------------------------------------------------------------------------
__global__ __launch_bounds__(256) void reduce_norm_rows(
    const unsigned short* __restrict__ Sexp, const unsigned short* __restrict__ Part,
    float* __restrict__ out)
{
    const int g = blockIdx.x;           // 0..8191
    const int batch = g >> 12;
    const int r = g & 4095;
    const int t = threadIdx.x;
    const int wv = t >> 6, ln = t & 63;

    // denominator
    const unsigned short* srow = Sexp + (size_t)batch * 16777216 + (size_t)r * 4096;
    us8 a = ((const us8*)srow)[t];
    us8 b = ((const us8*)srow)[t + 256];
    float s = 0.f;
#pragma unroll
    for (int j = 0; j < 8; ++j) s += bf16_to_f32(a[j]) + bf16_to_f32(b[j]);
#pragma unroll
    for (int off = 32; off > 0; off >>= 1) s += __shfl_down(s, off, 64);
    __shared__ float red[4];
    if (ln == 0) red[wv] = s;
    __syncthreads();
    const float inv = 1.f / (red[0] + red[1] + red[2] + red[3]);

    // reduce 2 bf16 partials + normalize; threads 0..191 each own 4 cols
    if (t < 192) {
        const int c = t * 4;
        float4 acc = {0.f, 0.f, 0.f, 0.f};
#pragma unroll
        for (int sgroup = 0; sgroup < 2; ++sgroup) {
            const unsigned short* p = Part
                + ((size_t)(sgroup * 2 + batch) * 4096 + r) * 768 + c;
            ushort4 u = *(const ushort4*)p;
            acc.x += bf16_to_f32(u.x);
            acc.y += bf16_to_f32(u.y);
            acc.z += bf16_to_f32(u.z);
            acc.w += bf16_to_f32(u.w);
        }
        float4 o;
        o.x = acc.x * inv; o.y = acc.y * inv; o.z = acc.z * inv; o.w = acc.w * inv;
        *(float4*)(out + (size_t)g * 768 + c) = o;
    }
}

// ---------------------------------------------------------------------------
extern "C" void kernel_launch(void* const* d_in, const int* in_sizes, int n_in,
                              void* d_out, int out_size, void* d_ws, size_t ws_size,
                              hipStream_t stream) {
    const float* x  = (const float*)d_in[0];   // [2,4096,768]
    const float* Wq = (const float*)d_in[1];   // [768,768]
    const float* Wk = (const float*)d_in[2];
    const float* Wv = (const float*)d_in[3];
    float* out = (float*)d_out;                // [2,4096,768] fp32

    char* base = (char*)d_ws;
    size_t off = 0;
    auto alloc = [&](size_t b) { char* p = base + off; off += (b + 255) & ~(size_t)255; return p; };

    unsigned short* Xbf = (unsigned short*)alloc(8192ull * 768 * 2);   // x as bf16
    unsigned short* WqT = (unsigned short*)alloc(768ull * 768 * 2);    // W^T bf16, x3 contiguous
    unsigned short* WkT = (unsigned short*)alloc(768ull * 768 * 2);
    unsigned short* WvT = (unsigned short*)alloc(768ull * 768 * 2);
    unsigned short* Qb  = (unsigned short*)alloc(8192ull * 768 * 2);   // Q,K bf16, contiguous
    unsigned short* Kb  = (unsigned short*)alloc(8192ull * 768 * 2);
    unsigned short* Vt  = (unsigned short*)alloc(768ull * 8192 * 2);   // V^T bf16 [768,8192]
    unsigned short* Sexp = (unsigned short*)alloc(2ull * 4096 * 4096 * 2); // exp(scores) bf16
    unsigned short* Part = (unsigned short*)alloc(4ull * 3145728 * 2); // split-K partials, bf16
    (void)ws_size; (void)in_sizes; (void)n_in; (void)out_size; (void)WkT;

    // 1) x -> bf16 and W -> W^T bf16 (fused, 1024-thread blocks)
    prep<<<dim3(3264), dim3(1024), 0, stream>>>(x, Xbf, Wq, Wk, Wv, WqT, WkT, WvT);
    // 2) Q,K = Xbf . W^T^T  (NT; z selects Wq/Wk)
    gemm_nt<unsigned short><<<dim3(6, 64, 2), dim3(256), 0, stream>>>(
        Xbf, WqT, Qb, 768, 768, 768, 768,
        /*sA*/ 0, /*sB*/ 589824, /*sC*/ 6291456, 1.0f);
    // 3) V^T = WvT . Xbf^T  (NT) -> [768, 8192]
    gemm_nt<unsigned short><<<dim3(64, 6, 1), dim3(256), 0, stream>>>(
        WvT, Xbf, Vt, 768, 768, 768, 8192, 0, 0, 0, 1.0f);
    // 4) Sexp = exp(Q.K^T / sqrt(768)) bf16 -- 256^2 core v3 (counted vmcnt,
    //    2-tile prefetch, XCD swizzle)
    gemm_s_exp2<<<dim3(512), dim3(512), 0, stream>>>(
        Qb, Kb, Sexp, 0.03608439182435161f);
    // 5) O' = Sexp . V via 2-way split-K, 256x192 tiles = 256 blocks exact fill
    gemm_splitk2<<<dim3(256), dim3(512), 0, stream>>>(Sexp, Vt, Part);
    // 6) fused denominator + partial-reduce + normalize
    reduce_norm_rows<<<dim3(8192), dim3(256), 0, stream>>>(Sexp, Part, out);
}

// Round 4
// 252.185 us; speedup vs baseline: 1.2112x; 1.0727x over previous
//
#include <hip/hip_runtime.h>

typedef __bf16 bf16x8 __attribute__((ext_vector_type(8)));
typedef float f32x4 __attribute__((ext_vector_type(4)));
typedef unsigned short us8 __attribute__((ext_vector_type(8)));

#define GAS __attribute__((address_space(1)))
#define LAS __attribute__((address_space(3)))

__device__ __forceinline__ unsigned short f32_to_bf16(float f) {
    unsigned int u = __float_as_uint(f);
    u += 0x7FFFu + ((u >> 16) & 1u);   // round-to-nearest-even
    return (unsigned short)(u >> 16);
}

__device__ __forceinline__ float bf16_to_f32(unsigned short h) {
    return __uint_as_float((unsigned int)h << 16);
}

__device__ __forceinline__ void load16(const unsigned short* g, unsigned short* l) {
    // async global->LDS, 16B per lane; LDS dest is wave-uniform base + lane*16
    __builtin_amdgcn_global_load_lds((GAS unsigned int*)g, (LAS unsigned int*)l, 16, 0, 0);
}

// ---------------------------------------------------------------------------
// prep (1024 threads): blocks [0,1536) convert x fp32->bf16 float4-wide
// (1536*1024 == 8192*768/4 exactly); blocks [1536,3264) transpose the three
// 768x768 weights to bf16 (24x24 tiles x 3 weights = 1728 blocks).
// ---------------------------------------------------------------------------
__global__ __launch_bounds__(1024) void prep(
    const float* __restrict__ x, unsigned short* __restrict__ Xbf,
    const float* __restrict__ W0, const float* __restrict__ W1, const float* __restrict__ W2,
    unsigned short* __restrict__ T0, unsigned short* __restrict__ T1, unsigned short* __restrict__ T2)
{
    __shared__ float tile[32][33];
    const int id = blockIdx.x;
    const int t = threadIdx.x;
    if (id < 1536) {
        int i = id * 1024 + t;
        float4 v = ((const float4*)x)[i];
        ushort4 o;
        o.x = f32_to_bf16(v.x); o.y = f32_to_bf16(v.y);
        o.z = f32_to_bf16(v.z); o.w = f32_to_bf16(v.w);
        ((ushort4*)Xbf)[i] = o;
    } else {
        const int tid = id - 1536;               // 0..1727
        const int z = tid / 576, rem = tid % 576;
        const int by = rem / 24, bx = rem % 24;
        const float* W = (z == 0) ? W0 : (z == 1) ? W1 : W2;
        unsigned short* T = (z == 0) ? T0 : (z == 1) ? T1 : T2;
        const int r0 = by * 32, c0 = bx * 32;
        const int tx = t & 31, ty = t >> 5;      // 32x32
        tile[ty][tx] = W[(size_t)(r0 + ty) * 768 + c0 + tx];
        __syncthreads();
        T[(size_t)(c0 + ty) * 768 + r0 + tx] = f32_to_bf16(tile[tx][ty]);
    }
}

// ---------------------------------------------------------------------------
// NT GEMM (m97 structure + XOR bank-swizzle): C = alpha * A[M,K] . B[N,K]^T
// (kept for the small QK / V^T projections)
// ---------------------------------------------------------------------------
template <typename CT>
__global__ __launch_bounds__(256) void gemm_nt(
    const unsigned short* __restrict__ A, const unsigned short* __restrict__ B,
    CT* __restrict__ C, int K, int lda, int ldb, int ldc,
    size_t sA, size_t sB, size_t sC, float alpha)
{
    A += (size_t)blockIdx.z * sA;
    B += (size_t)blockIdx.z * sB;
    C += (size_t)blockIdx.z * sC;
    const int m0 = blockIdx.y * 128;
    const int n0 = blockIdx.x * 128;
    const int t = threadIdx.x;
    const int lane = t & 63;
    const int w = t >> 6;
    const int wm = (w >> 1) * 64;   // wave row offset in tile
    const int wn = (w & 1) * 64;    // wave col offset in tile

    __shared__ unsigned short At[128 * 64];
    __shared__ unsigned short Bt[128 * 64];

    f32x4 acc[4][4];
#pragma unroll
    for (int i = 0; i < 4; ++i)
#pragma unroll
        for (int j = 0; j < 4; ++j) acc[i][j] = (f32x4){0.f, 0.f, 0.f, 0.f};

    const int r15 = lane & 15;
    const int qa = lane >> 4;       // fragment chunk index within 32-elem half

    for (int k0 = 0; k0 < K; k0 += 64) {
#pragma unroll
        for (int i = 0; i < 4; ++i) {
            const int c = i * 256 + t;            // LDS chunk id (8 bf16 each)
            const int row = c >> 3;
            const int cc = (c & 7) ^ (row & 7);   // swizzled global source chunk
            load16(A + (size_t)(m0 + row) * lda + k0 + cc * 8, &At[c * 8]);
            load16(B + (size_t)(n0 + row) * ldb + k0 + cc * 8, &Bt[c * 8]);
        }
        __syncthreads();

#pragma unroll
        for (int ks = 0; ks < 2; ++ks) {
            bf16x8 af[4], bf[4];
#pragma unroll
            for (int mi = 0; mi < 4; ++mi) {
                const int row = wm + mi * 16 + r15;
                af[mi] = *(const bf16x8*)&At[row * 64 + (((ks << 2) + qa) ^ (row & 7)) * 8];
            }
#pragma unroll
            for (int ni = 0; ni < 4; ++ni) {
                const int row = wn + ni * 16 + r15;
                bf[ni] = *(const bf16x8*)&Bt[row * 64 + (((ks << 2) + qa) ^ (row & 7)) * 8];
            }
#pragma unroll
            for (int mi = 0; mi < 4; ++mi)
#pragma unroll
                for (int ni = 0; ni < 4; ++ni)
                    acc[mi][ni] = __builtin_amdgcn_mfma_f32_16x16x32_bf16(
                        af[mi], bf[ni], acc[mi][ni], 0, 0, 0);
        }
        __syncthreads();
    }

    // epilogue: C/D layout col=lane&15, row=(lane>>4)*4+reg  [m89/m91 verified]
    const int cr = (lane >> 4) * 4;
#pragma unroll
    for (int mi = 0; mi < 4; ++mi) {
#pragma unroll
        for (int ni = 0; ni < 4; ++ni) {
            const int gm = m0 + wm + mi * 16 + cr;
            const int gn = n0 + wn + ni * 16 + r15;
#pragma unroll
            for (int r = 0; r < 4; ++r) {
                float v = alpha * acc[mi][ni][r];
                if constexpr (sizeof(CT) == 2)
                    C[(size_t)(gm + r) * ldc + gn] = (CT)f32_to_bf16(v);
                else
                    C[(size_t)(gm + r) * ldc + gn] = v;
            }
        }
    }
}

// ---------------------------------------------------------------------------
// 256xBN-tile NT GEMM core v4. BK=64, 8 waves (2M x 4N, each 128 x BN/4).
// Ring-2 LDS, 2-tile prefetch, counted vmcnt (T4), and -- new in v4 --
// a MONOLITHIC tile body with only 2 barriers per K-tile:
//   vmcnt(L) ; s_barrier                  // tile t staged & visible
//   { ks=0: 12 ds_read_b128 frags, 32 MFMA ; ks=1: same }   // compiler
//     interleaves fine-grained lgkmcnt(N) so LDS drain overlaps MFMA issue
//   s_barrier                             // all waves done reading buf b
//   stage(b, t+2)                         // restage freed buffer
// The R3 4-phase lockstep (8 barriers + manual lgkmcnt(0) per phase) forced
// LDS and MFMA pipes to alternate; removing it lets waves desync and the
// compiler software-pipeline reads into the MFMA stream (m97 asm evidence).
// MFMA K-order per accumulator unchanged -> numerics identical.
// ---------------------------------------------------------------------------
template <int NT, int BN64, bool EXP>
__device__ __forceinline__ void gemm256_core(
    const unsigned short* __restrict__ A, const unsigned short* __restrict__ B,
    unsigned short* __restrict__ C,
    int m0, int n0, int lda, int ldb, int ldc, float alpha)
{
    constexpr int BN = BN64 * 64;        // 256 or 192
    __shared__ unsigned short As[2][256 * 64];
    __shared__ unsigned short Bs[2][BN * 64];

    const int t = threadIdx.x;          // 0..511
    const int lane = t & 63;
    const int w = t >> 6;               // 0..7
    const int wm = (w >> 2) * 128;      // 0 / 128
    const int wn = (w & 3) * (BN / 4);  // wave col offset
    const int r15 = lane & 15;
    const int qa = lane >> 4;           // 0..3

    // Per-thread staging addresses: 4 A-loads + BN64 B-loads per K-tile.
    const unsigned short* srcA[4];
    int dstA[4];
#pragma unroll
    for (int i = 0; i < 4; ++i) {
        const int c = i * 512 + t;
        const int row = c >> 3;
        const int cc = (c & 7) ^ (row & 7);
        srcA[i] = A + (size_t)(m0 + row) * lda + cc * 8;
        dstA[i] = c * 8;
    }
    const unsigned short* srcB[BN64];
    int dstB[BN64];
#pragma unroll
    for (int i = 0; i < BN64; ++i) {
        const int c = i * 512 + t;
        const int row = c >> 3;
        const int cc = (c & 7) ^ (row & 7);
        srcB[i] = B + (size_t)(n0 + row) * ldb + cc * 8;
        dstB[i] = c * 8;
    }

    auto stage = [&](int buf, int kbase) {
#pragma unroll
        for (int i = 0; i < 4; ++i)
            load16(srcA[i] + kbase, &As[buf][dstA[i]]);
#pragma unroll
        for (int i = 0; i < BN64; ++i)
            load16(srcB[i] + kbase, &Bs[buf][dstB[i]]);
    };

    // Fragment LDS offsets (elements), same XOR swizzle as staging.
    int offA[8][2], offB[BN64][2];
#pragma unroll
    for (int mi = 0; mi < 8; ++mi) {
        const int row = wm + mi * 16 + r15;
#pragma unroll
        for (int ks = 0; ks < 2; ++ks)
            offA[mi][ks] = row * 64 + (((ks << 2) + qa) ^ (row & 7)) * 8;
    }
#pragma unroll
    for (int ni = 0; ni < BN64; ++ni) {
        const int row = wn + ni * 16 + r15;
#pragma unroll
        for (int ks = 0; ks < 2; ++ks)
            offB[ni][ks] = row * 64 + (((ks << 2) + qa) ^ (row & 7)) * 8;
    }

    f32x4 acc[8][BN64];
#pragma unroll
    for (int i = 0; i < 8; ++i)
#pragma unroll
        for (int j = 0; j < BN64; ++j) acc[i][j] = (f32x4){0.f, 0.f, 0.f, 0.f};

    // Prologue: stage tiles 0 and 1 (fills the ring).
    stage(0, 0);
    stage(1, 64);

    for (int tt = 0; tt < NT; ++tt) {
        const int b = tt & 1;

        // Counted wait: all but the newest L loads (tile t+1's) retired =>
        // tile t's staging landed. Last tile: full drain (loads are old).
        if (tt == NT - 1) {
            asm volatile("s_waitcnt vmcnt(0)" ::: "memory");
        } else if constexpr (BN64 == 4) {
            asm volatile("s_waitcnt vmcnt(8)" ::: "memory");
        } else {
            asm volatile("s_waitcnt vmcnt(7)" ::: "memory");
        }
        __builtin_amdgcn_s_barrier();

        // Monolithic tile body: compiler-scheduled ds_read <-> MFMA overlap.
#pragma unroll
        for (int ks = 0; ks < 2; ++ks) {
            bf16x8 aA[8], bB[BN64];
#pragma unroll
            for (int i = 0; i < 8; ++i)
                aA[i] = *(const bf16x8*)&As[b][offA[i][ks]];
#pragma unroll
            for (int ni = 0; ni < BN64; ++ni)
                bB[ni] = *(const bf16x8*)&Bs[b][offB[ni][ks]];
#pragma unroll
            for (int i = 0; i < 8; ++i)
#pragma unroll
                for (int ni = 0; ni < BN64; ++ni)
                    acc[i][ni] = __builtin_amdgcn_mfma_f32_16x16x32_bf16(
                        aA[i], bB[ni], acc[i][ni], 0, 0, 0);
        }

        asm volatile("" ::: "memory");
        __builtin_amdgcn_s_barrier();   // all waves done reading buf b

        // Restage the freed buffer with tile t+2 (wait is ~1 full tile away).
        if (tt + 2 < NT) stage(b, (tt + 2) << 6);
    }

    // epilogue: C/D layout col=lane&15, row=(lane>>4)*4+reg
    const int cr = (lane >> 4) * 4;
#pragma unroll
    for (int mi = 0; mi < 8; ++mi) {
#pragma unroll
        for (int ni = 0; ni < BN64; ++ni) {
            const int gm = m0 + wm + mi * 16 + cr;
            const int gn = n0 + wn + ni * 16 + r15;
#pragma unroll
            for (int r = 0; r < 4; ++r) {
                float v = alpha * acc[mi][ni][r];
                if constexpr (EXP) v = __expf(v);
                C[(size_t)(gm + r) * ldc + gn] = f32_to_bf16(v);
            }
        }
    }
}

// Sexp = exp(alpha * Q.K^T) bf16. 1-D grid 512, 512 threads. XCD swizzle:
// xcd = (x>>3) | ((y>>3)<<1) | (batch<<2); local = (x&7) + 8*(y&7).
// Within an XCD: 8 x-blocks share each Q-panel, 8 y-blocks share each K-panel.
__global__ __launch_bounds__(512, 2) void gemm_s_exp2(
    const unsigned short* __restrict__ Q, const unsigned short* __restrict__ Kb,
    unsigned short* __restrict__ Sexp, float alpha)
{
    const int f = blockIdx.x;            // 0..511
    const int xcd = f & 7;
    const int local = f >> 3;            // 0..63
    const int x = (xcd & 1) * 8 + (local & 7);
    const int y = ((xcd >> 1) & 1) * 8 + (local >> 3);
    const int bb = xcd >> 2;
    const unsigned short* A = Q + (size_t)bb * 3145728;
    const unsigned short* B = Kb + (size_t)bb * 3145728;
    unsigned short* C = Sexp + (size_t)bb * 16777216;
    gemm256_core<12, 4, true>(A, B, C, y * 256, x * 256, 768, 768, 4096, alpha);
}

// Split-K O-GEMM, BN=192 -> 256 blocks = EXACT one round.
// z = split*2 + batch, K-chunk 2048 (NT=32). Part[z][4096][768] bf16.
// XCD swizzle: xcd = 2*z + (y>>3); local = j + 4*(y&7). Within an XCD all
// 4 n-blocks share each A(Sexp)-panel and 8 y-blocks share each V-panel.
__global__ __launch_bounds__(512, 2) void gemm_splitk2(
    const unsigned short* __restrict__ P, const unsigned short* __restrict__ Vt,
    unsigned short* __restrict__ Part)
{
    const int f = blockIdx.x;            // 0..255
    const int xcd = f & 7;
    const int local = f >> 3;            // 0..31
    const int j = local & 3;             // n-block 0..3
    const int y = (xcd & 1) * 8 + (local >> 2);   // m-block 0..15
    const int z = xcd >> 1;              // 0..3
    const int batch = z & 1;
    const int split = z >> 1;            // 0..1
    const unsigned short* A = P + (size_t)batch * 16777216 + (size_t)split * 2048;
    const unsigned short* B = Vt + (size_t)batch * 4096 + (size_t)split * 2048;
    unsigned short* C = Part + (size_t)z * 3145728;
    gemm256_core<32, 3, false>(A, B, C, y * 256, j * 192, 4096, 8192, 768, 1.0f);
}

// ---------------------------------------------------------------------------
// Fused denominator + partial reduce + normalize. One block per output row g:
//   lsum = sum of Sexp[batch][r][:]   (4096 bf16, shuffle+LDS reduce)
//   out[g][c] = (sum_s Part[s*2+batch][r][c]) / lsum   (bf16 partials, fp32 out)
// ---------------------------------------------------------------------------
__global__ __launch_bounds__(256) void reduce_norm_rows(
    const unsigned short* __restrict__ Sexp, const unsigned short* __restrict__ Part,
    float* __restrict__ out)
{
    const int g = blockIdx.x;           // 0..8191
    const int batch = g >> 12;
    const int r = g & 4095;
    const int t = threadIdx.x;
    const int wv = t >> 6, ln = t & 63;

    // denominator
    const unsigned short* srow = Sexp + (size_t)batch * 16777216 + (size_t)r * 4096;
    us8 a = ((const us8*)srow)[t];
    us8 b = ((const us8*)srow)[t + 256];
    float s = 0.f;
#pragma unroll
    for (int j = 0; j < 8; ++j) s += bf16_to_f32(a[j]) + bf16_to_f32(b[j]);
#pragma unroll
    for (int off = 32; off > 0; off >>= 1) s += __shfl_down(s, off, 64);
    __shared__ float red[4];
    if (ln == 0) red[wv] = s;
    __syncthreads();
    const float inv = 1.f / (red[0] + red[1] + red[2] + red[3]);

    // reduce 2 bf16 partials + normalize; threads 0..191 each own 4 cols
    if (t < 192) {
        const int c = t * 4;
        float4 acc = {0.f, 0.f, 0.f, 0.f};
#pragma unroll
        for (int sgroup = 0; sgroup < 2; ++sgroup) {
            const unsigned short* p = Part
                + ((size_t)(sgroup * 2 + batch) * 4096 + r) * 768 + c;
            ushort4 u = *(const ushort4*)p;
            acc.x += bf16_to_f32(u.x);
            acc.y += bf16_to_f32(u.y);
            acc.z += bf16_to_f32(u.z);
            acc.w += bf16_to_f32(u.w);
        }
        float4 o;
        o.x = acc.x * inv; o.y = acc.y * inv; o.z = acc.z * inv; o.w = acc.w * inv;
        *(float4*)(out + (size_t)g * 768 + c) = o;
    }
}

// ---------------------------------------------------------------------------
extern "C" void kernel_launch(void* const* d_in, const int* in_sizes, int n_in,
                              void* d_out, int out_size, void* d_ws, size_t ws_size,
                              hipStream_t stream) {
    const float* x  = (const float*)d_in[0];   // [2,4096,768]
    const float* Wq = (const float*)d_in[1];   // [768,768]
    const float* Wk = (const float*)d_in[2];
    const float* Wv = (const float*)d_in[3];
    float* out = (float*)d_out;                // [2,4096,768] fp32

    char* base = (char*)d_ws;
    size_t off = 0;
    auto alloc = [&](size_t b) { char* p = base + off; off += (b + 255) & ~(size_t)255; return p; };

    unsigned short* Xbf = (unsigned short*)alloc(8192ull * 768 * 2);   // x as bf16
    unsigned short* WqT = (unsigned short*)alloc(768ull * 768 * 2);    // W^T bf16, x3 contiguous
    unsigned short* WkT = (unsigned short*)alloc(768ull * 768 * 2);
    unsigned short* WvT = (unsigned short*)alloc(768ull * 768 * 2);
    unsigned short* Qb  = (unsigned short*)alloc(8192ull * 768 * 2);   // Q,K bf16, contiguous
    unsigned short* Kb  = (unsigned short*)alloc(8192ull * 768 * 2);
    unsigned short* Vt  = (unsigned short*)alloc(768ull * 8192 * 2);   // V^T bf16 [768,8192]
    unsigned short* Sexp = (unsigned short*)alloc(2ull * 4096 * 4096 * 2); // exp(scores) bf16
    unsigned short* Part = (unsigned short*)alloc(4ull * 3145728 * 2); // split-K partials, bf16
    (void)ws_size; (void)in_sizes; (void)n_in; (void)out_size; (void)WkT;

    // 1) x -> bf16 and W -> W^T bf16 (fused, 1024-thread blocks)
    prep<<<dim3(3264), dim3(1024), 0, stream>>>(x, Xbf, Wq, Wk, Wv, WqT, WkT, WvT);
    // 2) Q,K = Xbf . W^T^T  (NT; z selects Wq/Wk)
    gemm_nt<unsigned short><<<dim3(6, 64, 2), dim3(256), 0, stream>>>(
        Xbf, WqT, Qb, 768, 768, 768, 768,
        /*sA*/ 0, /*sB*/ 589824, /*sC*/ 6291456, 1.0f);
    // 3) V^T = WvT . Xbf^T  (NT) -> [768, 8192]
    gemm_nt<unsigned short><<<dim3(64, 6, 1), dim3(256), 0, stream>>>(
        WvT, Xbf, Vt, 768, 768, 768, 8192, 0, 0, 0, 1.0f);
    // 4) Sexp = exp(Q.K^T / sqrt(768)) bf16 -- 256^2 core v4 (2 barriers/tile,
    //    counted vmcnt, 2-tile prefetch, XCD swizzle)
    gemm_s_exp2<<<dim3(512), dim3(512), 0, stream>>>(
        Qb, Kb, Sexp, 0.03608439182435161f);
    // 5) O' = Sexp . V via 2-way split-K, 256x192 tiles = 256 blocks exact fill
    gemm_splitk2<<<dim3(256), dim3(512), 0, stream>>>(Sexp, Vt, Part);
    // 6) fused denominator + partial-reduce + normalize
    reduce_norm_rows<<<dim3(8192), dim3(256), 0, stream>>>(Sexp, Part, out);
}